// Round 5
// baseline (331.823 us; speedup 1.0000x reference)
//
#include <hip/hip_runtime.h>

#define H 1024
#define W 1024
#define KS 21
#define RAD 10
#define TX 224            // output cols per block (256 staged cols, 1 col/thread)
#define NXB 5             // 5*224 = 1120 >= 1024; last block masks
#define YO 64             // output rows per block
#define R 8               // rows per step
#define NSTEP (YO / R)    // 8
#define VSTR 257          // vbuf row stride (odd -> <=2-way banks everywhere)
#define HSTR 225          // hbuf row stride (odd)
#define WIN (KS + R - 1)  // 28-deep vertical register window

// jnp 'reflect' (no edge repeat) for indices in [-(W-1), 2W-2]
__device__ __forceinline__ int reflect1024(int i) {
    return 1023 - abs(1023 - abs(i));
}

// LDS-only barrier. __syncthreads() emits `s_waitcnt vmcnt(0) lgkmcnt(0)` before
// s_barrier, draining the column prefetch + output stores at EVERY step (the
// round-4 stall). We only need LDS ordering: wait lgkmcnt(0) (own ds ops
// retired), then raw s_barrier. Global loads keep their compiler-inserted
// counted vmcnt(N) at the point of register use.
__device__ __forceinline__ void lds_barrier() {
    asm volatile("s_waitcnt lgkmcnt(0)" ::: "memory");
    __builtin_amdgcn_s_barrier();
    asm volatile("" ::: "memory");   // no LDS op may sink above the barrier
}

__global__ __launch_bounds__(256, 8)   // cap VGPR at 64 -> 8 blocks/CU resident
void gauss_fused(const float* __restrict__ in, const float* __restrict__ k2d,
                 float* __restrict__ out) {
    __shared__ float vbuf[R][VSTR];   // v-conv results, col j = global col x0-12+j
    __shared__ float hbuf[R][HSTR];   // h-conv results, col c = global col x0+c
    __shared__ float rw_s[KS];        // total 15508 B -> 8 blocks/CU (wave cap)

    const int t = threadIdx.x;
    const int x0 = blockIdx.x * TX;
    const int y0 = blockIdx.y * YO;
    const long long plane = (long long)blockIdx.z * (long long)(H * W);
    const float* inp = in + plane;
    float* outp = out + plane;

    // separable 1D factor: k2d = outer(r,r), r[i] = k2d[i][c]/sqrt(k2d[c][c])
    if (t < KS) {
        float c = k2d[RAD * KS + RAD];
        rw_s[t] = k2d[t * KS + RAD] / sqrtf(c);
    }
    __syncthreads();   // once, outside the hot loop — full drain is fine here

    // wave-uniform weights -> SGPRs (v_fma takes one SGPR operand)
    float w[KS];
#pragma unroll
    for (int j = 0; j < KS; ++j)
        w[j] = __uint_as_float(__builtin_amdgcn_readfirstlane(__float_as_uint(rw_s[j])));

    // per-thread fixed input column; lane t -> global col x0-12+t (x-reflect folded once)
    const int xc = reflect1024(x0 - 12 + t);
    const float* colp = inp + xc;
    const bool yint = (y0 != 0) && (y0 != H - YO);   // interior y: no reflect needed

    // ---- preload: win rows y0-10 .. y0+9, prefetch rows y0+10 .. y0+17 ----
    float win[WIN];
#pragma unroll
    for (int q = 0; q < WIN - R; ++q)                // 20 rows
        win[q] = colp[reflect1024(y0 - RAD + q) << 10];
    float pf[R];
#pragma unroll
    for (int j = 0; j < R; ++j)
        pf[j] = colp[reflect1024(y0 + RAD + j) << 10];

#pragma unroll 1
    for (int s = 0; s < NSTEP; ++s) {
        // complete the 28-row window (counted vmcnt wait inserted here by compiler)
#pragma unroll
        for (int j = 0; j < R; ++j) win[WIN - R + j] = pf[j];

        // issue next step's 8 loads now; they stay in flight across BOTH barriers
        if (s < NSTEP - 1) {
            const int nbase = y0 + R * s + WIN - RAD;     // +18
            if (yint) {
                const float* p = colp + ((long long)nbase << 10);
#pragma unroll
                for (int j = 0; j < R; ++j) pf[j] = p[j << 10];
            } else {
#pragma unroll
                for (int j = 0; j < R; ++j) pf[j] = colp[reflect1024(nbase + j) << 10];
            }
        }

        // ---- v-conv: 8 outputs/thread, pure registers ----
#pragma unroll
        for (int k = 0; k < R; ++k) {
            float acc = 0.f;
#pragma unroll
            for (int j = 0; j < KS; ++j) acc += w[j] * win[k + j];
            vbuf[k][t] = acc;                  // banks (k+t)%32: 2-way, free
        }

        // ---- store previous step's results (barrier shadow) ----
        // hbuf(s-1) synced at b2(s-1); h-conv rewrites hbuf only after b1, by which
        // point every wave's hbuf reads here have retired (b1 waits lgkmcnt(0)).
        if (s > 0 && t < TX && x0 + t < W) {
            const int ybase = y0 + R * (s - 1);
#pragma unroll
            for (int k = 0; k < R; ++k)
                outp[((ybase + k) << 10) + (x0 + t)] = hbuf[k][t];
        }
        lds_barrier();   // b1: vbuf ready; stores/loads remain in flight

        // ---- h-conv: row hr = t>>5 (0..7), cols 7*hs .. 7*hs+6 ----
        // reads vbuf[hr][7hs+2+q]: banks (hr+7hs+2+q)%32, 7 coprime 32 -> 2-way, free
        {
            const int hr = t >> 5, hs = t & 31;
            const int base = 7 * hs;
            float hw[27];
#pragma unroll
            for (int q = 0; q < 27; ++q) hw[q] = vbuf[hr][base + 2 + q];
#pragma unroll
            for (int i = 0; i < 7; ++i) {
                float acc = 0.f;
#pragma unroll
                for (int j = 0; j < KS; ++j) acc += w[j] * hw[i + j];
                hbuf[hr][base + i] = acc;      // banks (hr+7hs+i)%32: 2-way
            }
        }
        lds_barrier();   // b2: vbuf reads retired (next v-conv may rewrite), hbuf complete

        // slide the vertical window by R
#pragma unroll
        for (int q = 0; q < WIN - R; ++q) win[q] = win[q + R];
    }

    // ---- flush: store the last step's results ----
    if (t < TX && x0 + t < W) {
        const int ybase = y0 + YO - R;
#pragma unroll
        for (int k = 0; k < R; ++k)
            outp[((ybase + k) << 10) + (x0 + t)] = hbuf[k][t];
    }
}

extern "C" void kernel_launch(void* const* d_in, const int* in_sizes, int n_in,
                              void* d_out, int out_size, void* d_ws, size_t ws_size,
                              hipStream_t stream) {
    const float* x = (const float*)d_in[0];
    const float* k = (const float*)d_in[1];
    float* out = (float*)d_out;
    const int n = in_sizes[0] / (H * W);  // batch*channels = 32
    dim3 grid(NXB, H / YO, n);            // 5 x 16 x 32 = 2560 blocks -> 8 resident/CU
    gauss_fused<<<grid, dim3(256), 0, stream>>>(x, k, out);
}

// Round 6
// 249.270 us; speedup vs baseline: 1.3312x; 1.3312x over previous
//
#include <hip/hip_runtime.h>

#define H 1024
#define W 1024
#define KS 21
#define RAD 10
#define TX 224            // output cols per block (256 staged cols, 1 col/thread)
#define NXB 5             // 5*224 = 1120 >= 1024; last block masks
#define YO 64             // output rows per block
#define R 8               // rows per step
#define NSTEP (YO / R)    // 8
#define VSTR 257          // vbuf row stride (odd -> <=2-way banks everywhere)
#define HSTR 225          // hbuf row stride (odd)
#define WIN (KS + R - 1)  // 28-deep vertical register window

// jnp 'reflect' (no edge repeat) for indices in [-(W-1), 2W-2]
__device__ __forceinline__ int reflect1024(int i) {
    return 1023 - abs(1023 - abs(i));
}

// LDS-only barrier. __syncthreads() emits `s_waitcnt vmcnt(0) lgkmcnt(0)` before
// s_barrier, draining the column prefetch + output stores at EVERY step. We only
// need LDS ordering: wait lgkmcnt(0) (own ds ops retired), then raw s_barrier.
// Global loads keep their compiler-inserted counted vmcnt(N) at point of use.
__device__ __forceinline__ void lds_barrier() {
    asm volatile("s_waitcnt lgkmcnt(0)" ::: "memory");
    __builtin_amdgcn_s_barrier();
    asm volatile("" ::: "memory");   // no LDS op may sink above the barrier
}

// (256,8) in round 5 forced VGPR=32 -> massive scratch spill (WRITE 131->288MB).
// (256,6): allocator budget ~85, natural usage ~40-48, runtime residency still
// 8 blocks/CU because actual VGPR <= 64 and LDS 15.5KB allows 10.
__global__ __launch_bounds__(256, 6)
void gauss_fused(const float* __restrict__ in, const float* __restrict__ k2d,
                 float* __restrict__ out) {
    __shared__ float vbuf[R][VSTR];   // v-conv results, col j = global col x0-12+j
    __shared__ float hbuf[R][HSTR];   // h-conv results, col c = global col x0+c
    __shared__ float rw_s[KS];        // total 15508 B

    const int t = threadIdx.x;
    const int x0 = blockIdx.x * TX;
    const int y0 = blockIdx.y * YO;
    const long long plane = (long long)blockIdx.z * (long long)(H * W);
    const float* inp = in + plane;
    float* outp = out + plane;

    // separable 1D factor: k2d = outer(r,r), r[i] = k2d[i][c]/sqrt(k2d[c][c])
    if (t < KS) {
        float c = k2d[RAD * KS + RAD];
        rw_s[t] = k2d[t * KS + RAD] / sqrtf(c);
    }
    __syncthreads();   // once, outside the hot loop — full drain is fine here

    // wave-uniform weights -> SGPRs (v_fma takes one SGPR operand)
    float w[KS];
#pragma unroll
    for (int j = 0; j < KS; ++j)
        w[j] = __uint_as_float(__builtin_amdgcn_readfirstlane(__float_as_uint(rw_s[j])));

    // per-thread fixed input column; lane t -> global col x0-12+t (x-reflect folded once)
    const int xc = reflect1024(x0 - 12 + t);
    const float* colp = inp + xc;
    const bool yint = (y0 != 0) && (y0 != H - YO);   // interior y: no reflect needed

    // ---- preload: win rows y0-10 .. y0+9, prefetch rows y0+10 .. y0+17 ----
    float win[WIN];
#pragma unroll
    for (int q = 0; q < WIN - R; ++q)                // 20 rows
        win[q] = colp[reflect1024(y0 - RAD + q) << 10];
    float pf[R];
#pragma unroll
    for (int j = 0; j < R; ++j)
        pf[j] = colp[reflect1024(y0 + RAD + j) << 10];

#pragma unroll 1
    for (int s = 0; s < NSTEP; ++s) {
        // complete the 28-row window (counted vmcnt wait inserted here by compiler)
#pragma unroll
        for (int j = 0; j < R; ++j) win[WIN - R + j] = pf[j];

        // issue next step's 8 loads now; they stay in flight across BOTH barriers
        if (s < NSTEP - 1) {
            const int nbase = y0 + R * s + WIN - RAD;     // +18
            if (yint) {
                const float* p = colp + ((long long)nbase << 10);
#pragma unroll
                for (int j = 0; j < R; ++j) pf[j] = p[j << 10];
            } else {
#pragma unroll
                for (int j = 0; j < R; ++j) pf[j] = colp[reflect1024(nbase + j) << 10];
            }
        }

        // ---- v-conv: 8 outputs/thread, pure registers ----
#pragma unroll
        for (int k = 0; k < R; ++k) {
            float acc = 0.f;
#pragma unroll
            for (int j = 0; j < KS; ++j) acc += w[j] * win[k + j];
            vbuf[k][t] = acc;                  // banks (k+t)%32: 2-way, free
        }

        // ---- store previous step's results (barrier shadow) ----
        // hbuf(s-1) synced at b2(s-1); h-conv rewrites hbuf only after b1, by which
        // point every wave's hbuf reads here have retired (b1 waits lgkmcnt(0)).
        if (s > 0 && t < TX && x0 + t < W) {
            const int ybase = y0 + R * (s - 1);
#pragma unroll
            for (int k = 0; k < R; ++k)
                outp[((ybase + k) << 10) + (x0 + t)] = hbuf[k][t];
        }
        lds_barrier();   // b1: vbuf ready; stores/loads remain in flight

        // ---- h-conv: row hr = t>>5 (0..7), cols 7*hs .. 7*hs+6 ----
        // reads vbuf[hr][7hs+2+q]: banks (hr+7hs+2+q)%32, 7 coprime 32 -> 2-way, free
        {
            const int hr = t >> 5, hs = t & 31;
            const int base = 7 * hs;
            float hw[27];
#pragma unroll
            for (int q = 0; q < 27; ++q) hw[q] = vbuf[hr][base + 2 + q];
#pragma unroll
            for (int i = 0; i < 7; ++i) {
                float acc = 0.f;
#pragma unroll
                for (int j = 0; j < KS; ++j) acc += w[j] * hw[i + j];
                hbuf[hr][base + i] = acc;      // banks (hr+7hs+i)%32: 2-way
            }
        }
        lds_barrier();   // b2: vbuf reads retired (next v-conv may rewrite), hbuf complete

        // slide the vertical window by R
#pragma unroll
        for (int q = 0; q < WIN - R; ++q) win[q] = win[q + R];
    }

    // ---- flush: store the last step's results ----
    if (t < TX && x0 + t < W) {
        const int ybase = y0 + YO - R;
#pragma unroll
        for (int k = 0; k < R; ++k)
            outp[((ybase + k) << 10) + (x0 + t)] = hbuf[k][t];
    }
}

extern "C" void kernel_launch(void* const* d_in, const int* in_sizes, int n_in,
                              void* d_out, int out_size, void* d_ws, size_t ws_size,
                              hipStream_t stream) {
    const float* x = (const float*)d_in[0];
    const float* k = (const float*)d_in[1];
    float* out = (float*)d_out;
    const int n = in_sizes[0] / (H * W);  // batch*channels = 32
    dim3 grid(NXB, H / YO, n);            // 5 x 16 x 32 = 2560 blocks -> 8 resident/CU
    gauss_fused<<<grid, dim3(256), 0, stream>>>(x, k, out);
}